// Round 1
// baseline (11.175 us; speedup 1.0000x reference)
//
#include <hip/hip_runtime.h>

#define NBLK 256
#define NTHR 256

// Stage 1: weighted sums S = sum(w * e), S2 = sum(w * e^2), e = (y - y_hat)^2,
// w = (row index along dim1) + 1. Per-block partials written to d_ws.
__global__ __launch_bounds__(NTHR) void stoch_partial(
    const float4* __restrict__ y,
    const float4* __restrict__ yh,
    double* __restrict__ ws,
    int n4)
{
    int tid = blockIdx.x * blockDim.x + threadIdx.x;
    double s = 0.0, s2 = 0.0;

    // Layout: [B][N=1024][D=64] fp32 -> 16 float4 per (b,i) row.
    for (int idx = tid; idx < n4; idx += NBLK * NTHR) {
        float4 a = y[idx];
        float4 b = yh[idx];
        int i = (idx >> 4) & 1023;          // row index within dim 1
        double w = (double)(i + 1);
        float d0 = a.x - b.x, d1 = a.y - b.y, d2 = a.z - b.z, d3 = a.w - b.w;
        float e0 = d0 * d0, e1 = d1 * d1, e2 = d2 * d2, e3 = d3 * d3;
        double se  = (double)e0 + (double)e1 + (double)e2 + (double)e3;
        double se2 = (double)e0 * e0 + (double)e1 * e1
                   + (double)e2 * e2 + (double)e3 * e3;
        s  += w * se;
        s2 += w * se2;
    }

    // wave-64 butterfly reduce
    for (int off = 32; off > 0; off >>= 1) {
        s  += __shfl_down(s,  off, 64);
        s2 += __shfl_down(s2, off, 64);
    }

    __shared__ double sh[2][NTHR / 64];
    int wave = threadIdx.x >> 6;
    int lane = threadIdx.x & 63;
    if (lane == 0) { sh[0][wave] = s; sh[1][wave] = s2; }
    __syncthreads();

    if (threadIdx.x == 0) {
        double ts = 0.0, ts2 = 0.0;
        #pragma unroll
        for (int wv = 0; wv < NTHR / 64; ++wv) { ts += sh[0][wv]; ts2 += sh[1][wv]; }
        ws[2 * blockIdx.x]     = ts;
        ws[2 * blockIdx.x + 1] = ts2;
    }
}

// Stage 2: reduce NBLK partials, finish the unbiased-variance formula.
__global__ __launch_bounds__(NTHR) void stoch_final(
    const double* __restrict__ ws,
    float* __restrict__ out,
    double M)
{
    int tid = threadIdx.x;                  // NTHR == NBLK: one partial per thread
    double s  = ws[2 * tid];
    double s2 = ws[2 * tid + 1];

    for (int off = 32; off > 0; off >>= 1) {
        s  += __shfl_down(s,  off, 64);
        s2 += __shfl_down(s2, off, 64);
    }

    __shared__ double sh[2][NTHR / 64];
    int wave = tid >> 6;
    int lane = tid & 63;
    if (lane == 0) { sh[0][wave] = s; sh[1][wave] = s2; }
    __syncthreads();

    if (tid == 0) {
        double S = 0.0, S2 = 0.0;
        #pragma unroll
        for (int wv = 0; wv < NTHR / 64; ++wv) { S += sh[0][wv]; S2 += sh[1][wv]; }
        double var = (S2 - S * S / M) / (M - 1.0);
        out[0] = (float)var;
    }
}

extern "C" void kernel_launch(void* const* d_in, const int* in_sizes, int n_in,
                              void* d_out, int out_size, void* d_ws, size_t ws_size,
                              hipStream_t stream) {
    const float4* y  = (const float4*)d_in[0];
    const float4* yh = (const float4*)d_in[1];
    double* ws = (double*)d_ws;
    float* out = (float*)d_out;

    const int n_elem = in_sizes[0];         // B*N*D = 8*1024*64 = 524288
    const int n4 = n_elem / 4;

    // M = B * N(N+1)/2 * D  (static expanded length of the repeat)
    const double B = 8.0, N = 1024.0, D = 64.0;
    const double M = B * (N * (N + 1.0) * 0.5) * D;   // 268,697,600

    stoch_partial<<<NBLK, NTHR, 0, stream>>>(y, yh, ws, n4);
    stoch_final<<<1, NTHR, 0, stream>>>(ws, out, M);
}